// Round 11
// baseline (156.264 us; speedup 1.0000x reference)
//
#include <hip/hip_runtime.h>

#define KK 4096
#define NN 11008
#define NGRP 32
#define WS_RS_OFF  131072    // ws: [0,128K) aperm bf16
#define WS_SZ_OFF  139264    // [136K,+1.41M) SZ[n][g]
#define WS_PK_OFF  2097152   // [2M,+22.5M) packed nibbles, MFMA-permuted

using short8  = __attribute__((ext_vector_type(8))) short;
using float4v = __attribute__((ext_vector_type(4))) float;

static __device__ __forceinline__ unsigned int pack_bf16(float lo, float hi) {
    unsigned int ul = __builtin_bit_cast(unsigned int, lo);
    unsigned int uh = __builtin_bit_cast(unsigned int, hi);
    ul = (ul + 0x7FFFu + ((ul >> 16) & 1u)) >> 16;
    uh = (uh + 0x7FFFu + ((uh >> 16) & 1u)) & 0xFFFF0000u;
    return ul | uh;
}
static __device__ __forceinline__ float bf16val(float f) {
    unsigned int u = __builtin_bit_cast(unsigned int, f);
    u = (u + 0x7FFFu + ((u >> 16) & 1u)) & 0xFFFF0000u;
    return __builtin_bit_cast(float, u);
}

// Fused: b<5504 -> compact qweight (LINEAR read: block = 2 rows = 16KB
//        contiguous; 64B/thread runs). Dest 64B per (n,g): dword at
//        byte g*64+quad*16+t*4 holds low-bytes of orig words g*64+t*16+quad*4..+4
//        => hot kernel's single 16B load/lane feeds all 4 MFMAs.
//        5504-5535 -> aperm; 5536-5567 -> rowsum; 5568-5911 -> SZ.
__global__ __launch_bounds__(256) void compact_prep_kernel(
    const float* __restrict__ A, const int* __restrict__ qweight,
    const float* __restrict__ scales, const float* __restrict__ zeros,
    unsigned short* __restrict__ wsA, float* __restrict__ rowsum,
    float* __restrict__ SZ, unsigned char* __restrict__ packed)
{
    const int b = blockIdx.x, t = threadIdx.x;
    if (b < 5504) {
        const int r  = t >> 7;            // row within block's 2 rows
        const int g  = (t >> 2) & 31;     // group
        const int tt = t & 3;             // MFMA t-index
        const size_t n = (size_t)b * 2 + r;
        const int4* src = (const int4*)(qweight + n * 2048 + g * 64 + tt * 16);
        unsigned char* dst = packed + n * 2048 + g * 64 + tt * 4;
        #pragma unroll
        for (int q = 0; q < 4; ++q) {     // int4 q = orig words tt*16+q*4..+4
            int4 v = src[q];
            unsigned int d = ((unsigned int)v.x & 0xFFu)
                           | (((unsigned int)v.y & 0xFFu) << 8)
                           | (((unsigned int)v.z & 0xFFu) << 16)
                           | (((unsigned int)v.w & 0xFFu) << 24);
            *(unsigned int*)(dst + q * 16) = d;
        }
    } else if (b < 5536) {
        const int tid = (b - 5504) * 256 + t;   // aperm chunk c=k/32 at [c*512,+512)
        const int c = tid >> 6, l = tid & 63;
        const float* src = A + (size_t)(l & 15) * KK + c * 32 + (l >> 4) * 8;
        float4v x0 = *(const float4v*)src;
        float4v x1 = *(const float4v*)(src + 4);
        union { short8 s8; unsigned int u[4]; } p;
        p.u[0] = pack_bf16(x0[0], x0[1]);
        p.u[1] = pack_bf16(x0[2], x0[3]);
        p.u[2] = pack_bf16(x1[0], x1[1]);
        p.u[3] = pack_bf16(x1[2], x1[3]);
        *(short8*)(wsA + (size_t)tid * 8) = p.s8;
    } else if (b < 5568) {
        const int sid = (b - 5536) * 16 + (t >> 4);   // m*32+g
        const int m = sid >> 5, g = sid & 31, j = t & 15;
        const float* p = A + (size_t)m * KK + g * 128 + j * 8;
        float4v x0 = *(const float4v*)p;
        float4v x1 = *(const float4v*)(p + 4);
        float sum = bf16val(x0[0]) + bf16val(x0[1]) + bf16val(x0[2]) + bf16val(x0[3])
                  + bf16val(x1[0]) + bf16val(x1[1]) + bf16val(x1[2]) + bf16val(x1[3]);
        sum += __shfl_xor(sum, 1, 16);
        sum += __shfl_xor(sum, 2, 16);
        sum += __shfl_xor(sum, 4, 16);
        sum += __shfl_xor(sum, 8, 16);
        if (j == 0) rowsum[sid] = sum;
    } else {
        const int e0 = (b - 5568) * 1024 + t * 4;     // 344 blocks cover 352256
        float4v s4 = *(const float4v*)(scales + e0);
        float4v z4 = *(const float4v*)(zeros + e0);
        float4v r;
        #pragma unroll
        for (int j = 0; j < 4; ++j) r[j] = s4[j] * (128.0f + z4[j]);
        *(float4v*)(SZ + e0) = r;
    }
}

// init_out: out[m][n] = bias[n] - sum_g SZ[n][g]*rowsum[m][g]
__global__ __launch_bounds__(256) void init_out_kernel(
    const float* __restrict__ bias, const float* __restrict__ SZ,
    const float* __restrict__ rowsum, float* __restrict__ out)
{
    __shared__ float rs[16][32];
    const int t = threadIdx.x;
    rs[t >> 5][t & 31]       = rowsum[t];
    rs[(t >> 5) + 8][t & 31] = rowsum[t + 256];
    __syncthreads();
    const int n0 = blockIdx.x * 16;
    const int m = t >> 4, nn = t & 15, ng = n0 + nn;
    const float* szr = SZ + (size_t)ng * NGRP;
    float corr = 0.f;
    #pragma unroll
    for (int g = 0; g < 32; ++g)
        corr = __builtin_fmaf(szr[g], rs[m][g], corr);
    out[(size_t)m * NN + ng] = bias[ng] - corr;
}

// Hot kernel (R9 structure, 4x fewer W bytes): 5504 blocks = 688 n-tiles x 8
// k-slices, 4 waves, wave = one 128-k group. ONE 16B W-load/lane (64B lines
// fully consumed), 4 aperm loads, no hot-loop barrier.
__global__ __launch_bounds__(256) void qgemm_kernel(
    const unsigned char*  __restrict__ packed,   // (11008, 2048) B permuted
    const float*          __restrict__ scales,   // (11008, 32)
    const unsigned short* __restrict__ aperm,    // fragment-linear bf16 A
    float*                __restrict__ out)      // (16, 11008) fp32
{
    const int nt = blockIdx.x >> 3, slice = blockIdx.x & 7;
    const int n0 = nt * 16;
    const int wid = threadIdx.x >> 6, lane = threadIdx.x & 63;
    const int nl = lane & 15, quad = lane >> 4;
    const int n = n0 + nl;
    const int g = slice * 4 + wid;               // this wave's group (0..31)

    const int4* wp = (const int4*)(packed + (size_t)n * 2048 + g * 64 + quad * 16);
    const unsigned short* ap = aperm + (size_t)g * 2048 + lane * 8;

    int4   wv = *wp;                              // dword t = MFMA t's 8 weights
    short8 a0 = *(const short8*)(ap);
    short8 a1 = *(const short8*)(ap + 512);
    short8 a2 = *(const short8*)(ap + 1024);
    short8 a3 = *(const short8*)(ap + 1536);
    const float s = scales[n * NGRP + g];

    float4v acc = {0.f, 0.f, 0.f, 0.f};
    const unsigned int dv[4] = {(unsigned int)wv.x, (unsigned int)wv.y,
                                (unsigned int)wv.z, (unsigned int)wv.w};
    short8 av[4] = {a0, a1, a2, a3};
    #pragma unroll
    for (int t = 0; t < 4; ++t) {
        const unsigned int d = dv[t];
        const unsigned int c0 = d, c1 = d >> 8, c2 = d >> 16, c3 = d >> 24;
        union { short8 s8; unsigned int u[4]; } bf;   // exact bf16(128+q)
        bf.u[0] = (c0 & 0xFu) | ((c0 << 12) & 0x000F0000u) | 0x43004300u;
        bf.u[1] = (c1 & 0xFu) | ((c1 << 12) & 0x000F0000u) | 0x43004300u;
        bf.u[2] = (c2 & 0xFu) | ((c2 << 12) & 0x000F0000u) | 0x43004300u;
        bf.u[3] = (c3 & 0xFu) | ((c3 << 12) & 0x000F0000u) | 0x43004300u;
        acc = __builtin_amdgcn_mfma_f32_16x16x32_bf16(av[t], bf.s8, acc, 0, 0, 0);
    }

    __shared__ float red[4][16][16];
    #pragma unroll
    for (int r = 0; r < 4; ++r)
        red[wid][quad * 4 + r][nl] = s * acc[r];   // C/D: m=quad*4+r, n=nl [m89]
    __syncthreads();

    const int t = threadIdx.x;
    const int m = t >> 4, nn = t & 15;
    float val = red[0][m][nn] + red[1][m][nn] + red[2][m][nn] + red[3][m][nn];
    atomicAdd(&out[(size_t)m * NN + n0 + nn], val);
}

extern "C" void kernel_launch(void* const* d_in, const int* in_sizes, int n_in,
                              void* d_out, int out_size, void* d_ws, size_t ws_size,
                              hipStream_t stream) {
    const float* A       = (const float*)d_in[0];
    const int*   qweight = (const int*)d_in[1];
    const float* scales  = (const float*)d_in[2];
    const float* zeros   = (const float*)d_in[3];
    const float* bias    = (const float*)d_in[4];
    float*       out     = (float*)d_out;

    unsigned short* wsA   = (unsigned short*)d_ws;
    float* rowsum         = (float*)((char*)d_ws + WS_RS_OFF);
    float* SZ             = (float*)((char*)d_ws + WS_SZ_OFF);
    unsigned char* packed = (unsigned char*)d_ws + WS_PK_OFF;

    compact_prep_kernel<<<dim3(5912), dim3(256), 0, stream>>>(
        A, qweight, scales, zeros, wsA, rowsum, SZ, packed);
    init_out_kernel<<<dim3(688), dim3(256), 0, stream>>>(bias, SZ, rowsum, out);
    qgemm_kernel<<<dim3(5504), dim3(256), 0, stream>>>(packed, scales, wsA, out);
}